// Round 4
// baseline (651.432 us; speedup 1.0000x reference)
//
#include <hip/hip_runtime.h>
#include <hip/hip_bf16.h>
#include <math.h>

typedef short bf16x8 __attribute__((ext_vector_type(8)));
typedef float f32x4 __attribute__((ext_vector_type(4)));

constexpr int CIN = 32, COUT = 64, D = 16, H = 32, W = 32;

// ---------------- ws layout ----------------
// [0, 884736)          : wtp bf16 [cls8][t27][co64][ci32]
// [1MB, 1MB+33554432)  : xT  bf16 [n16][id16][ih32][iw32][ci32]
constexpr size_t WS_XT_OFF = 1u << 20;
constexpr size_t WS_NEED   = WS_XT_OFF + 33554432u;

__global__ void prep_w(const float* __restrict__ w, unsigned short* __restrict__ wtp) {
    int idx = blockIdx.x * 256 + threadIdx.x;            // 442368 total
    int ci  = idx & 31;
    int co  = (idx >> 5) & 63;
    int tt  = idx >> 11;                                  // cls*27 + t
    int t   = tt % 27, cls = tt / 27;
    int td = t / 9, th = (t / 3) % 3, tw = t % 3;
    int pd = (cls >> 2) & 1, ph = (cls >> 1) & 1, pw = cls & 1;
    int kd = pd + 2 * td, kh = ph + 2 * th, kw = pw + 2 * tw;
    float v = 0.f;
    if (kd < 5 && kh < 5 && kw < 5)
        v = w[(ci * COUT + co) * 125 + kd * 25 + kh * 5 + kw];
    __hip_bfloat16 b = __float2bfloat16(v);
    wtp[idx] = *reinterpret_cast<unsigned short*>(&b);
}

// x [n][ci][id][ih][iw] fp32 -> xT [n][id][ih][iw][ci] bf16
__global__ void transpose_x(const float* __restrict__ x, unsigned short* __restrict__ xT) {
    __shared__ float tile[32 * 33];
    int bid = blockIdx.x;                    // n*512 + id*32 + ih
    int ih = bid & 31, id = (bid >> 5) & 15, n = bid >> 9;
    int tid = threadIdx.x;
    int lw = tid & 31, g = tid >> 5;         // g in [0,8)
#pragma unroll
    for (int p = 0; p < 4; ++p) {
        int ci = g + p * 8;
        tile[lw * 33 + ci] = x[((((size_t)n * CIN + ci) * D + id) * H + ih) * W + lw];
    }
    __syncthreads();
    unsigned short* op = xT + ((((size_t)n * D + id) * H + ih) * W) * CIN;
#pragma unroll
    for (int p = 0; p < 4; ++p) {
        int iw = g + p * 8;
        __hip_bfloat16 b = __float2bfloat16(tile[iw * 33 + lw]);
        op[iw * 32 + lw] = *reinterpret_cast<unsigned short*>(&b);
    }
}

// One (cls, window-chunk) item: fully unrolled taps; NW windows starting at
// local window AWL (absolute window = wave-half*5 + AWL, folded into addrj).
template <int PD, int PH, int PW, int NW, int AWL>
__device__ __forceinline__ void run_item(
    const unsigned short* __restrict__ wtp, const char* __restrict__ xsb,
    const unsigned (&addrj)[2][4], int laneB, float (&omax)[5][4])
{
    constexpr int CLS = PD * 4 + PH * 2 + PW;
    f32x4 acc[NW][2][4];
#pragma unroll
    for (int w = 0; w < NW; ++w)
#pragma unroll
        for (int mt = 0; mt < 2; ++mt)
#pragma unroll
            for (int nt = 0; nt < 4; ++nt) acc[w][mt][nt] = (f32x4){0.f, 0.f, 0.f, 0.f};

#pragma unroll
    for (int td = 0; td < 3 - PD; ++td)
#pragma unroll
    for (int th = 0; th < 3 - PH; ++th)
#pragma unroll
    for (int tw = 0; tw < 3 - PW; ++tw) {
        const int t = td * 9 + th * 3 + tw;
        const unsigned short* bp = wtp + (CLS * 27 + t) * 2048 + laneB;
        bf16x8 bf0 = *(const bf16x8*)(bp);
        bf16x8 bf1 = *(const bf16x8*)(bp + 512);
        bf16x8 bf2 = *(const bf16x8*)(bp + 1024);
        bf16x8 bf3 = *(const bf16x8*)(bp + 1536);
        const int dtR = td * 160 + th * 32 + tw;
        const int dts = td + th + tw;
#pragma unroll
        for (int w = 0; w < NW; ++w) {
            const int j   = (3 * (AWL + w) + 6 - dts) & 3;
            const int off = (3 * (AWL + w) - dtR) * 64;
#pragma unroll
            for (int mt = 0; mt < 2; ++mt) {
                bf16x8 af = *(const bf16x8*)(xsb + (int)addrj[mt][j] + off);
                acc[w][mt][0] = __builtin_amdgcn_mfma_f32_16x16x32_bf16(af, bf0, acc[w][mt][0], 0, 0, 0);
                acc[w][mt][1] = __builtin_amdgcn_mfma_f32_16x16x32_bf16(af, bf1, acc[w][mt][1], 0, 0, 0);
                acc[w][mt][2] = __builtin_amdgcn_mfma_f32_16x16x32_bf16(af, bf2, acc[w][mt][2], 0, 0, 0);
                acc[w][mt][3] = __builtin_amdgcn_mfma_f32_16x16x32_bf16(af, bf3, acc[w][mt][3], 0, 0, 0);
            }
        }
    }
    // fold this item's accs into omax (per-lane partial: this lane's 8 rows)
#pragma unroll
    for (int w = 0; w < NW; ++w)
#pragma unroll
        for (int nt = 0; nt < 4; ++nt) {
            float m = fmaxf(fmaxf(fmaxf(acc[w][0][nt][0], acc[w][0][nt][1]),
                                  fmaxf(acc[w][0][nt][2], acc[w][0][nt][3])),
                            fmaxf(fmaxf(acc[w][1][nt][0], acc[w][1][nt][1]),
                                  fmaxf(acc[w][1][nt][2], acc[w][1][nt][3])));
            omax[AWL + w][nt] = fmaxf(omax[AWL + w][nt], m);
        }
}

__global__ __launch_bounds__(256, 3) void main_k(
    const unsigned short* __restrict__ wtp, const unsigned short* __restrict__ xT,
    const float* __restrict__ bias, float* __restrict__ out)
{
    __shared__ unsigned short Xs[25600];           // 51200 B, swizzled
    int bx = blockIdx.x;                           // (n*5+d0)*10 + h0, 800 total
    int h0 = bx % 10;
    int d0 = (bx / 10) % 5;
    int n  = bx / 50;
    int tid = threadIdx.x;

    // ---- stage Xs (swizzled) ----
    int id0 = 3 * d0 - 1, ih0 = 3 * h0 - 1;
    for (int i = tid; i < 3200; i += 256) {
        int cb = i & 3, ww = (i >> 2) & 31, hl = (i >> 7) % 5, dd = i / 640;
        int id = id0 + dd, ih = ih0 + hl, iw = ww - 1;
        float4 v = {0.f, 0.f, 0.f, 0.f};
        if (id >= 0 && ih >= 0 && iw >= 0)
            v = ((const float4*)(xT + ((((size_t)n * D + id) * H + ih) * W + iw) * 32))[cb];
        int R = (dd * 5 + hl) * 32 + ww;
        ((float4*)Xs)[R * 4 + (cb ^ ((dd + hl + ww) & 3))] = v;
    }

    int lane = tid & 63, wv = tid >> 6;
    int l15 = lane & 15, quad = lane >> 4;
    int wOff = (wv >> 1) * 5;                     // waves 0,1 -> wins 0-4; 2,3 -> 5-9
    int laneB = l15 * 32 + quad * 8;

    // per-(mt, swizzle-phase) A base addresses (bytes into Xs)
    unsigned addrj[2][4];
#pragma unroll
    for (int mt = 0; mt < 2; ++mt) {
        int row = mt * 16 + l15, pos = row < 27 ? row : 26;
        int a = pos / 9, b = (pos / 3) % 3, c = pos % 3;
        int P = ((a + 2) * 5 + (b + 2)) * 32 + (3 * wOff + 2 + c);
        int S = a + b + c + 3 * wOff;
#pragma unroll
        for (int j = 0; j < 4; ++j)
            addrj[mt][j] = (unsigned)(P * 64 + ((quad ^ ((S + j) & 3)) << 4));
    }

    float omax[5][4];
#pragma unroll
    for (int lw = 0; lw < 5; ++lw)
#pragma unroll
        for (int nt = 0; nt < 4; ++nt) omax[lw][nt] = -INFINITY;

    __syncthreads();
    const char* xsb = (const char*)Xs;

    // Balanced schedule: path A (waves 0,2) cost 313, path B (waves 1,3) cost 312.
    if ((wv & 1) == 0) {
        run_item<0,0,0,3,0>(wtp, xsb, addrj, laneB, omax);
        run_item<0,0,1,3,0>(wtp, xsb, addrj, laneB, omax);
        run_item<0,1,0,3,0>(wtp, xsb, addrj, laneB, omax);
        run_item<0,1,1,3,0>(wtp, xsb, addrj, laneB, omax);
        run_item<1,0,0,2,3>(wtp, xsb, addrj, laneB, omax);
        run_item<1,0,1,3,0>(wtp, xsb, addrj, laneB, omax);
        run_item<1,1,1,2,3>(wtp, xsb, addrj, laneB, omax);
    } else {
        run_item<0,0,0,2,3>(wtp, xsb, addrj, laneB, omax);
        run_item<0,0,1,2,3>(wtp, xsb, addrj, laneB, omax);
        run_item<0,1,0,2,3>(wtp, xsb, addrj, laneB, omax);
        run_item<0,1,1,2,3>(wtp, xsb, addrj, laneB, omax);
        run_item<1,0,0,3,0>(wtp, xsb, addrj, laneB, omax);
        run_item<1,0,1,2,3>(wtp, xsb, addrj, laneB, omax);
        run_item<1,1,0,3,0>(wtp, xsb, addrj, laneB, omax);
        run_item<1,1,0,2,3>(wtp, xsb, addrj, laneB, omax);
        run_item<1,1,1,3,0>(wtp, xsb, addrj, laneB, omax);
    }

    // ---- epilogue: cross-wave/cls/position max, bias, co-sum ----
    __syncthreads();                 // Xs dead; reuse as wm[w4][quad4][lw5][co64]
    float* wm = (float*)Xs;
#pragma unroll
    for (int lw = 0; lw < 5; ++lw)
#pragma unroll
        for (int nt = 0; nt < 4; ++nt)
            wm[((wv * 4 + quad) * 5 + lw) * 64 + nt * 16 + l15] = omax[lw][nt];
    __syncthreads();

    // wave wv reduces its windows: {0,1,2},{3,4},{5,6,7},{8,9}
    const int wst[4] = {0, 3, 5, 8};
    const int wct[4] = {3, 2, 3, 2};
    int elemBase = ((n * 5 + d0) * 10 + h0) * 10;
    float bco = bias[lane];
    for (int k = 0; k < wct[wv]; ++k) {
        int win = wst[wv] + k;
        int half = win / 5, lw = win % 5;
        float m = -INFINITY;
#pragma unroll
        for (int sq = 0; sq < 8; ++sq)   // 2 waves of this half x 4 quads
            m = fmaxf(m, wm[(((half * 2) * 4 + sq) * 5 + lw) * 64 + lane]);
        float v = m + bco;
#pragma unroll
        for (int off = 32; off > 0; off >>= 1) v += __shfl_xor(v, off);
        if (lane == 0) out[elemBase + win] = v;
    }
}

// ---------------- fallback (round-1 kernel, no ws needed) ----------------
__global__ __launch_bounds__(256) void fused_fallback(
    const float* __restrict__ x, const float* __restrict__ wsrc,
    const float* __restrict__ bias, float* __restrict__ out)
{
    __shared__ float xs[CIN * 125];
    __shared__ float wmax[4][64];
    const int b  = blockIdx.x;
    const int w0 = b % 10, h0 = (b / 10) % 10, d0 = (b / 100) % 5, n = b / 500;
    const int tid = threadIdx.x;
    const int id0 = 3 * d0 - 1, ih0 = 3 * h0 - 1, iw0 = 3 * w0 - 1;
    for (int e = tid; e < CIN * 125; e += 256) {
        int kk = e % 5, jj = (e / 5) % 5, ii = (e / 25) % 5, c = e / 125;
        int id = id0 + ii, ih = ih0 + jj, iw = iw0 + kk;
        float v = 0.f;
        if (id >= 0 && ih >= 0 && iw >= 0)
            v = x[(((n * CIN + c) * D + id) * H + ih) * W + iw];
        xs[e] = v;
    }
    __syncthreads();
    const int lane = tid & 63, wv = tid >> 6;
    float lmax = -INFINITY;
    for (int ccls = 0; ccls < 2; ++ccls) {
        const int cls = wv * 2 + ccls;
        const int pd = (cls >> 2) & 1, ph = (cls >> 1) & 1, pw = cls & 1;
        float acc[27];
#pragma unroll
        for (int i = 0; i < 27; ++i) acc[i] = 0.f;
        for (int ci = 0; ci < CIN; ++ci) {
            float wr[27];
#pragma unroll
            for (int t = 0; t < 27; ++t) {
                int td = t / 9, th = (t / 3) % 3, tw = t % 3;
                int kd = pd + 2 * td, kh = ph + 2 * th, kw = pw + 2 * tw;
                wr[t] = (kd < 5 && kh < 5 && kw < 5)
                          ? wsrc[((ci * 64 + lane) * 125) + kd * 25 + kh * 5 + kw] : 0.f;
            }
            const float* xb = xs + ci * 125;
#pragma unroll
            for (int td = 0; td < 3; ++td)
#pragma unroll
            for (int th = 0; th < 3; ++th)
#pragma unroll
            for (int tw = 0; tw < 3; ++tw) {
                const float wval = wr[(td * 3 + th) * 3 + tw];
#pragma unroll
                for (int a = 0; a < 3; ++a)
#pragma unroll
                for (int bb = 0; bb < 3; ++bb)
#pragma unroll
                for (int cc = 0; cc < 3; ++cc)
                    acc[(a * 3 + bb) * 3 + cc] +=
                        xb[(a + 2 - td) * 25 + (bb + 2 - th) * 5 + (cc + 2 - tw)] * wval;
            }
        }
#pragma unroll
        for (int i = 0; i < 27; ++i) lmax = fmaxf(lmax, acc[i]);
    }
    wmax[wv][lane] = lmax;
    __syncthreads();
    if (wv == 0) {
        float m = fmaxf(fmaxf(wmax[0][lane], wmax[1][lane]),
                        fmaxf(wmax[2][lane], wmax[3][lane]));
        m += bias[lane];
        for (int off = 32; off > 0; off >>= 1) m += __shfl_down(m, off);
        if (lane == 0) out[b] = m;
    }
}

extern "C" void kernel_launch(void* const* d_in, const int* in_sizes, int n_in,
                              void* d_out, int out_size, void* d_ws, size_t ws_size,
                              hipStream_t stream) {
    const float* x    = (const float*)d_in[0];
    const float* w    = (const float*)d_in[1];
    const float* bias = (const float*)d_in[2];
    float* out = (float*)d_out;

    if (ws_size >= WS_NEED) {
        unsigned short* wtp = (unsigned short*)d_ws;
        unsigned short* xT  = (unsigned short*)((char*)d_ws + WS_XT_OFF);
        prep_w<<<1728, 256, 0, stream>>>(w, wtp);
        transpose_x<<<8192, 256, 0, stream>>>(x, xT);
        main_k<<<800, 256, 0, stream>>>(wtp, xT, bias, out);
    } else {
        fused_fallback<<<8000, 256, 0, stream>>>(x, w, bias, out);
    }
}

// Round 5
// 233.521 us; speedup vs baseline: 2.7896x; 2.7896x over previous
//
#include <hip/hip_runtime.h>
#include <hip/hip_bf16.h>
#include <math.h>

typedef short bf16x8 __attribute__((ext_vector_type(8)));
typedef float f32x4 __attribute__((ext_vector_type(4)));

constexpr int CIN = 32, COUT = 64, D = 16, H = 32, W = 32;

// ---------------- ws layout ----------------
// [0, 884736)                     : wtp bf16 [cls8][t27][co64][ci32]
// [1MB, 1MB+33554432)             : xT  bf16 [n16][id16][ih32][iw32][ci32]
// [1MB+33554432, +16384000)       : partial f32 [cls8][elem8000][co64]
constexpr size_t WS_XT_OFF   = 1u << 20;
constexpr size_t WS_PART_OFF = WS_XT_OFF + 33554432u;
constexpr size_t WS_NEED     = WS_PART_OFF + 16384000u;

__global__ void prep_w(const float* __restrict__ w, unsigned short* __restrict__ wtp) {
    int idx = blockIdx.x * 256 + threadIdx.x;            // 442368 total
    int ci  = idx & 31;
    int co  = (idx >> 5) & 63;
    int tt  = idx >> 11;                                  // cls*27 + t
    int t   = tt % 27, cls = tt / 27;
    int td = t / 9, th = (t / 3) % 3, tw = t % 3;
    int pd = (cls >> 2) & 1, ph = (cls >> 1) & 1, pw = cls & 1;
    int kd = pd + 2 * td, kh = ph + 2 * th, kw = pw + 2 * tw;
    float v = 0.f;
    if (kd < 5 && kh < 5 && kw < 5)
        v = w[(ci * COUT + co) * 125 + kd * 25 + kh * 5 + kw];
    __hip_bfloat16 b = __float2bfloat16(v);
    wtp[idx] = *reinterpret_cast<unsigned short*>(&b);
}

// x [n][ci][id][ih][iw] fp32 -> xT [n][id][ih][iw][ci] bf16
__global__ void transpose_x(const float* __restrict__ x, unsigned short* __restrict__ xT) {
    __shared__ float tile[32 * 33];
    int bid = blockIdx.x;                    // n*512 + id*32 + ih
    int ih = bid & 31, id = (bid >> 5) & 15, n = bid >> 9;
    int tid = threadIdx.x;
    int lw = tid & 31, g = tid >> 5;         // g in [0,8)
#pragma unroll
    for (int p = 0; p < 4; ++p) {
        int ci = g + p * 8;
        tile[lw * 33 + ci] = x[((((size_t)n * CIN + ci) * D + id) * H + ih) * W + lw];
    }
    __syncthreads();
    unsigned short* op = xT + ((((size_t)n * D + id) * H + ih) * W) * CIN;
#pragma unroll
    for (int p = 0; p < 4; ++p) {
        int iw = g + p * 8;
        __hip_bfloat16 b = __float2bfloat16(tile[iw * 33 + lw]);
        op[iw * 32 + lw] = *reinterpret_cast<unsigned short*>(&b);
    }
}

// Flat software-pipelined tap loop: B-fragments for tap it+1 prefetched into
// registers while tap it's 6 A-reads + 24 MFMAs execute.
template <int NW>
__device__ __forceinline__ void do_compute(
    const unsigned short* __restrict__ wp, const unsigned short* __restrict__ Xs,
    const int (&R0)[3][2], const int (&s0)[3][2], int quad, int ci0, int l15,
    int ntd, int nth, int ntw, float (&omax)[3][4])
{
    f32x4 acc[NW][2][4];
#pragma unroll
    for (int w = 0; w < NW; ++w)
#pragma unroll
        for (int mt = 0; mt < 2; ++mt)
#pragma unroll
            for (int nt = 0; nt < 4; ++nt) acc[w][mt][nt] = (f32x4){0.f, 0.f, 0.f, 0.f};

    const unsigned short* bbase = wp + l15 * 32 + ci0;
    const int T = ntd * nth * ntw;

    // prefetch tap 0 (td=th=tw=0)
    bf16x8 nb0 = *(const bf16x8*)(bbase);
    bf16x8 nb1 = *(const bf16x8*)(bbase + 512);
    bf16x8 nb2 = *(const bf16x8*)(bbase + 1024);
    bf16x8 nb3 = *(const bf16x8*)(bbase + 1536);
    int ptd = 0, pth = 0, ptw = 0;     // coords of prefetched tap
    int ndtR = 0, ndts = 0;

#pragma unroll 1
    for (int it = 0; it < T; ++it) {
        // consume prefetched B (vmcnt wait lands here, after prev MFMAs)
        bf16x8 b0 = nb0, b1 = nb1, b2 = nb2, b3 = nb3;
        const int dtR = ndtR, dts = ndts;

        // advance prefetch tap (clamped; wave-uniform SALU)
        if (it + 1 < T) {
            ++ptw;
            if (ptw == ntw) { ptw = 0; ++pth; if (pth == nth) { pth = 0; ++ptd; } }
        }
        ndtR = ptd * 160 + pth * 32 + ptw;
        ndts = ptd + pth + ptw;
        const unsigned short* bq = bbase + (ptd * 9 + pth * 3 + ptw) * 2048;
        nb0 = *(const bf16x8*)(bq);
        nb1 = *(const bf16x8*)(bq + 512);
        nb2 = *(const bf16x8*)(bq + 1024);
        nb3 = *(const bf16x8*)(bq + 1536);

#pragma unroll
        for (int w = 0; w < NW; ++w) {
#pragma unroll
            for (int mt = 0; mt < 2; ++mt) {
                int s = (s0[w][mt] - dts) & 3;
                bf16x8 af = *(const bf16x8*)(Xs + (R0[w][mt] - dtR) * 32 + ((quad ^ s) << 3));
                acc[w][mt][0] = __builtin_amdgcn_mfma_f32_16x16x32_bf16(af, b0, acc[w][mt][0], 0, 0, 0);
                acc[w][mt][1] = __builtin_amdgcn_mfma_f32_16x16x32_bf16(af, b1, acc[w][mt][1], 0, 0, 0);
                acc[w][mt][2] = __builtin_amdgcn_mfma_f32_16x16x32_bf16(af, b2, acc[w][mt][2], 0, 0, 0);
                acc[w][mt][3] = __builtin_amdgcn_mfma_f32_16x16x32_bf16(af, b3, acc[w][mt][3], 0, 0, 0);
            }
        }
    }

#pragma unroll
    for (int w = 0; w < NW; ++w)
#pragma unroll
        for (int nt = 0; nt < 4; ++nt) {
            float m = acc[w][0][nt][0];
            m = fmaxf(m, acc[w][0][nt][1]);
            m = fmaxf(m, acc[w][0][nt][2]);
            m = fmaxf(m, acc[w][0][nt][3]);
            m = fmaxf(m, acc[w][1][nt][0]);
            m = fmaxf(m, acc[w][1][nt][1]);
            m = fmaxf(m, acc[w][1][nt][2]);
            m = fmaxf(m, acc[w][1][nt][3]);
            m = fmaxf(m, __shfl_xor(m, 16));
            m = fmaxf(m, __shfl_xor(m, 32));
            omax[w][nt] = m;
        }
}

__global__ __launch_bounds__(256, 2) void main_k(
    const unsigned short* __restrict__ wtp, const unsigned short* __restrict__ xT,
    float* __restrict__ partial)
{
    __shared__ unsigned short Xs[25600];           // 51200 B, swizzled
    int bx  = blockIdx.x;
    int cls = bx / 800;                            // cls-grouped for L2/I$ locality
    int e   = bx % 800;                            // (n*5+d0)*10 + h0
    int h0  = e % 10;
    int d0  = (e / 10) % 5;
    int n   = e / 50;
    int pd = (cls >> 2) & 1, ph = (cls >> 1) & 1, pw = cls & 1;
    int ntd = 3 - pd, nth = 3 - ph, ntw = 3 - pw;
    int tid = threadIdx.x;

    // ---- stage Xs (swizzled) ----
    int id0 = 3 * d0 - 1, ih0 = 3 * h0 - 1;
    for (int i = tid; i < 3200; i += 256) {
        int cb = i & 3, ww = (i >> 2) & 31, hl = (i >> 7) % 5, dd = i / 640;
        int id = id0 + dd, ih = ih0 + hl, iw = ww - 1;
        float4 v = {0.f, 0.f, 0.f, 0.f};
        if (id >= 0 && ih >= 0 && iw >= 0)
            v = ((const float4*)(xT + ((((size_t)n * D + id) * H + ih) * W + iw) * 32))[cb];
        int R = (dd * 5 + hl) * 32 + ww;
        ((float4*)Xs)[R * 4 + (cb ^ ((dd + hl + ww) & 3))] = v;
    }
    __syncthreads();

    int lane = tid & 63, wv = tid >> 6;
    int l15 = lane & 15, quad = lane >> 4, ci0 = quad * 8;
    const int starts[4] = {0, 3, 6, 8};
    const int cnts[4]   = {3, 3, 2, 2};
    int widx = (wv + h0) & 3;
    int wst = starts[widx], wcnt = cnts[widx];

    int R0[3][2], s0[3][2];
#pragma unroll
    for (int w = 0; w < 3; ++w)
#pragma unroll
        for (int mt = 0; mt < 2; ++mt) {
            int row = mt * 16 + l15;
            int pos = row < 27 ? row : 26;
            int a = pos / 9, b = (pos / 3) % 3, c = pos % 3;
            int w0v = (w < wcnt) ? (wst + w) : wst;
            R0[w][mt] = ((2 + a) * 5 + (2 + b)) * 32 + (3 * w0v + 2 + c);
            s0[w][mt] = a + b + c + 6 + 3 * w0v;   // >= max dts (6), so (s0-dts) >= 0
        }

    const unsigned short* wp = wtp + (size_t)cls * 27 * 2048;
    float omax[3][4];
    if (wcnt == 3) do_compute<3>(wp, Xs, R0, s0, quad, ci0, l15, ntd, nth, ntw, omax);
    else           do_compute<2>(wp, Xs, R0, s0, quad, ci0, l15, ntd, nth, ntw, omax);

    if (quad == 0) {
        int elemBase = ((n * 5 + d0) * 10 + h0) * 10;
        for (int w = 0; w < wcnt; ++w) {
            int elem = elemBase + wst + w;
            float* pp = partial + ((size_t)(cls * 8000 + elem)) * 64;
#pragma unroll
            for (int nt = 0; nt < 4; ++nt) pp[nt * 16 + l15] = omax[w][nt];
        }
    }
}

__global__ void finalize_k(const float* __restrict__ partial, const float* __restrict__ bias,
                           float* __restrict__ out)
{
    int tid = threadIdx.x;
    int el  = blockIdx.x * 4 + (tid >> 6);   // 2000 blocks, wave per elem
    int co  = tid & 63;
    float m = -INFINITY;
#pragma unroll
    for (int cls = 0; cls < 8; ++cls)
        m = fmaxf(m, partial[((size_t)(cls * 8000 + el)) * 64 + co]);
    float v = m + bias[co];
#pragma unroll
    for (int off = 32; off > 0; off >>= 1) v += __shfl_xor(v, off);
    if (co == 0) out[el] = v;
}

// ---------------- fallback (round-1 kernel, no ws needed) ----------------
__global__ __launch_bounds__(256) void fused_fallback(
    const float* __restrict__ x, const float* __restrict__ wsrc,
    const float* __restrict__ bias, float* __restrict__ out)
{
    __shared__ float xs[CIN * 125];
    __shared__ float wmax[4][64];
    const int b  = blockIdx.x;
    const int w0 = b % 10, h0 = (b / 10) % 10, d0 = (b / 100) % 5, n = b / 500;
    const int tid = threadIdx.x;
    const int id0 = 3 * d0 - 1, ih0 = 3 * h0 - 1, iw0 = 3 * w0 - 1;
    for (int e = tid; e < CIN * 125; e += 256) {
        int kk = e % 5, jj = (e / 5) % 5, ii = (e / 25) % 5, c = e / 125;
        int id = id0 + ii, ih = ih0 + jj, iw = iw0 + kk;
        float v = 0.f;
        if (id >= 0 && ih >= 0 && iw >= 0)
            v = x[(((n * CIN + c) * D + id) * H + ih) * W + iw];
        xs[e] = v;
    }
    __syncthreads();
    const int lane = tid & 63, wv = tid >> 6;
    float lmax = -INFINITY;
    for (int ccls = 0; ccls < 2; ++ccls) {
        const int cls = wv * 2 + ccls;
        const int pd = (cls >> 2) & 1, ph = (cls >> 1) & 1, pw = cls & 1;
        float acc[27];
#pragma unroll
        for (int i = 0; i < 27; ++i) acc[i] = 0.f;
        for (int ci = 0; ci < CIN; ++ci) {
            float wr[27];
#pragma unroll
            for (int t = 0; t < 27; ++t) {
                int td = t / 9, th = (t / 3) % 3, tw = t % 3;
                int kd = pd + 2 * td, kh = ph + 2 * th, kw = pw + 2 * tw;
                wr[t] = (kd < 5 && kh < 5 && kw < 5)
                          ? wsrc[((ci * 64 + lane) * 125) + kd * 25 + kh * 5 + kw] : 0.f;
            }
            const float* xb = xs + ci * 125;
#pragma unroll
            for (int td = 0; td < 3; ++td)
#pragma unroll
            for (int th = 0; th < 3; ++th)
#pragma unroll
            for (int tw = 0; tw < 3; ++tw) {
                const float wval = wr[(td * 3 + th) * 3 + tw];
#pragma unroll
                for (int a = 0; a < 3; ++a)
#pragma unroll
                for (int bb = 0; bb < 3; ++bb)
#pragma unroll
                for (int cc = 0; cc < 3; ++cc)
                    acc[(a * 3 + bb) * 3 + cc] +=
                        xb[(a + 2 - td) * 25 + (bb + 2 - th) * 5 + (cc + 2 - tw)] * wval;
            }
        }
#pragma unroll
        for (int i = 0; i < 27; ++i) lmax = fmaxf(lmax, acc[i]);
    }
    wmax[wv][lane] = lmax;
    __syncthreads();
    if (wv == 0) {
        float m = fmaxf(fmaxf(wmax[0][lane], wmax[1][lane]),
                        fmaxf(wmax[2][lane], wmax[3][lane]));
        m += bias[lane];
        for (int off = 32; off > 0; off >>= 1) m += __shfl_down(m, off);
        if (lane == 0) out[b] = m;
    }
}

extern "C" void kernel_launch(void* const* d_in, const int* in_sizes, int n_in,
                              void* d_out, int out_size, void* d_ws, size_t ws_size,
                              hipStream_t stream) {
    const float* x    = (const float*)d_in[0];
    const float* w    = (const float*)d_in[1];
    const float* bias = (const float*)d_in[2];
    float* out = (float*)d_out;

    if (ws_size >= WS_NEED) {
        unsigned short* wtp = (unsigned short*)d_ws;
        unsigned short* xT  = (unsigned short*)((char*)d_ws + WS_XT_OFF);
        float* partial      = (float*)((char*)d_ws + WS_PART_OFF);
        prep_w<<<1728, 256, 0, stream>>>(w, wtp);
        transpose_x<<<8192, 256, 0, stream>>>(x, xT);
        main_k<<<6400, 256, 0, stream>>>(wtp, xT, partial);
        finalize_k<<<2000, 256, 0, stream>>>(partial, bias, out);
    } else {
        fused_fallback<<<8000, 256, 0, stream>>>(x, w, bias, out);
    }
}

// Round 6
// 216.149 us; speedup vs baseline: 3.0138x; 1.0804x over previous
//
#include <hip/hip_runtime.h>
#include <hip/hip_bf16.h>
#include <math.h>

typedef short bf16x8 __attribute__((ext_vector_type(8)));
typedef float f32x4 __attribute__((ext_vector_type(4)));

constexpr int CIN = 32, COUT = 64, D = 16, H = 32, W = 32;

// ---------------- ws layout ----------------
// [0, 884736)                     : wtp bf16 [cls8][t27][co64][ci32]
// [1MB, 1MB+33554432)             : xT  bf16 [n16][id16][ih32][iw32][ci32]
// [1MB+33554432, +4096000)        : partial f32 [half2][elem8000][co64]
constexpr size_t WS_XT_OFF   = 1u << 20;
constexpr size_t WS_PART_OFF = WS_XT_OFF + 33554432u;
constexpr size_t WS_NEED     = WS_PART_OFF + 4096000u;

__global__ void prep_w(const float* __restrict__ w, unsigned short* __restrict__ wtp) {
    int idx = blockIdx.x * 256 + threadIdx.x;            // 442368 total
    int ci  = idx & 31;
    int co  = (idx >> 5) & 63;
    int tt  = idx >> 11;                                  // cls*27 + t
    int t   = tt % 27, cls = tt / 27;
    int td = t / 9, th = (t / 3) % 3, tw = t % 3;
    int pd = (cls >> 2) & 1, ph = (cls >> 1) & 1, pw = cls & 1;
    int kd = pd + 2 * td, kh = ph + 2 * th, kw = pw + 2 * tw;
    float v = 0.f;
    if (kd < 5 && kh < 5 && kw < 5)
        v = w[(ci * COUT + co) * 125 + kd * 25 + kh * 5 + kw];
    __hip_bfloat16 b = __float2bfloat16(v);
    wtp[idx] = *reinterpret_cast<unsigned short*>(&b);
}

// x [n][ci][id][ih][iw] fp32 -> xT [n][id][ih][iw][ci] bf16
__global__ void transpose_x(const float* __restrict__ x, unsigned short* __restrict__ xT) {
    __shared__ float tile[32 * 33];
    int bid = blockIdx.x;                    // n*512 + id*32 + ih
    int ih = bid & 31, id = (bid >> 5) & 15, n = bid >> 9;
    int tid = threadIdx.x;
    int lw = tid & 31, g = tid >> 5;         // g in [0,8)
#pragma unroll
    for (int p = 0; p < 4; ++p) {
        int ci = g + p * 8;
        tile[lw * 33 + ci] = x[((((size_t)n * CIN + ci) * D + id) * H + ih) * W + lw];
    }
    __syncthreads();
    unsigned short* op = xT + ((((size_t)n * D + id) * H + ih) * W) * CIN;
#pragma unroll
    for (int p = 0; p < 4; ++p) {
        int iw = g + p * 8;
        __hip_bfloat16 b = __float2bfloat16(tile[iw * 33 + lw]);
        op[iw * 32 + lw] = *reinterpret_cast<unsigned short*>(&b);
    }
}

// Flat software-pipelined tap loop (runtime trip counts). Folds max into omax.
template <int NW>
__device__ __forceinline__ void do_compute(
    const unsigned short* __restrict__ wp, const unsigned short* __restrict__ Xs,
    const int (&R0)[3][2], const int (&s0)[3][2], int quad, int ci0, int l15,
    int ntd, int nth, int ntw, float (&omax)[3][4])
{
    f32x4 acc[NW][2][4];
#pragma unroll
    for (int w = 0; w < NW; ++w)
#pragma unroll
        for (int mt = 0; mt < 2; ++mt)
#pragma unroll
            for (int nt = 0; nt < 4; ++nt) acc[w][mt][nt] = (f32x4){0.f, 0.f, 0.f, 0.f};

    const unsigned short* bbase = wp + l15 * 32 + ci0;
    const int T = ntd * nth * ntw;

    // prefetch tap 0 (td=th=tw=0)
    bf16x8 nb0 = *(const bf16x8*)(bbase);
    bf16x8 nb1 = *(const bf16x8*)(bbase + 512);
    bf16x8 nb2 = *(const bf16x8*)(bbase + 1024);
    bf16x8 nb3 = *(const bf16x8*)(bbase + 1536);
    int ptd = 0, pth = 0, ptw = 0;     // coords of prefetched tap
    int ndtR = 0, ndts = 0;

#pragma unroll 1
    for (int it = 0; it < T; ++it) {
        bf16x8 b0 = nb0, b1 = nb1, b2 = nb2, b3 = nb3;
        const int dtR = ndtR, dts = ndts;

        if (it + 1 < T) {
            ++ptw;
            if (ptw == ntw) { ptw = 0; ++pth; if (pth == nth) { pth = 0; ++ptd; } }
        }
        ndtR = ptd * 160 + pth * 32 + ptw;
        ndts = ptd + pth + ptw;
        const unsigned short* bq = bbase + (ptd * 9 + pth * 3 + ptw) * 2048;
        nb0 = *(const bf16x8*)(bq);
        nb1 = *(const bf16x8*)(bq + 512);
        nb2 = *(const bf16x8*)(bq + 1024);
        nb3 = *(const bf16x8*)(bq + 1536);

#pragma unroll
        for (int w = 0; w < NW; ++w) {
#pragma unroll
            for (int mt = 0; mt < 2; ++mt) {
                int s = (s0[w][mt] - dts) & 3;
                bf16x8 af = *(const bf16x8*)(Xs + (R0[w][mt] - dtR) * 32 + ((quad ^ s) << 3));
                acc[w][mt][0] = __builtin_amdgcn_mfma_f32_16x16x32_bf16(af, b0, acc[w][mt][0], 0, 0, 0);
                acc[w][mt][1] = __builtin_amdgcn_mfma_f32_16x16x32_bf16(af, b1, acc[w][mt][1], 0, 0, 0);
                acc[w][mt][2] = __builtin_amdgcn_mfma_f32_16x16x32_bf16(af, b2, acc[w][mt][2], 0, 0, 0);
                acc[w][mt][3] = __builtin_amdgcn_mfma_f32_16x16x32_bf16(af, b3, acc[w][mt][3], 0, 0, 0);
            }
        }
    }

#pragma unroll
    for (int w = 0; w < NW; ++w)
#pragma unroll
        for (int nt = 0; nt < 4; ++nt) {
            float m = acc[w][0][nt][0];
            m = fmaxf(m, acc[w][0][nt][1]);
            m = fmaxf(m, acc[w][0][nt][2]);
            m = fmaxf(m, acc[w][0][nt][3]);
            m = fmaxf(m, acc[w][1][nt][0]);
            m = fmaxf(m, acc[w][1][nt][1]);
            m = fmaxf(m, acc[w][1][nt][2]);
            m = fmaxf(m, acc[w][1][nt][3]);
            m = fmaxf(m, __shfl_xor(m, 16));
            m = fmaxf(m, __shfl_xor(m, 32));
            omax[w][nt] = fmaxf(omax[w][nt], m);
        }
}

__global__ __launch_bounds__(256, 2) void main_k(
    const unsigned short* __restrict__ wtp, const unsigned short* __restrict__ xT,
    float* __restrict__ partial)
{
    __shared__ unsigned short Xs[25600];           // 51200 B, swizzled
    int bx   = blockIdx.x;                         // slab*2 + half, 1600 total
    int half = bx & 1;
    int e    = bx >> 1;                            // (n*5+d0)*10 + h0
    int h0   = e % 10;
    int d0   = (e / 10) % 5;
    int n    = e / 50;
    int tid  = threadIdx.x;

    // ---- stage Xs (swizzled), once per block ----
    int id0 = 3 * d0 - 1, ih0 = 3 * h0 - 1;
    for (int i = tid; i < 3200; i += 256) {
        int cb = i & 3, ww = (i >> 2) & 31, hl = (i >> 7) % 5, dd = i / 640;
        int id = id0 + dd, ih = ih0 + hl, iw = ww - 1;
        float4 v = {0.f, 0.f, 0.f, 0.f};
        if (id >= 0 && ih >= 0 && iw >= 0)
            v = ((const float4*)(xT + ((((size_t)n * D + id) * H + ih) * W + iw) * 32))[cb];
        int R = (dd * 5 + hl) * 32 + ww;
        ((float4*)Xs)[R * 4 + (cb ^ ((dd + hl + ww) & 3))] = v;
    }
    __syncthreads();

    int lane = tid & 63, wv = tid >> 6;
    int l15 = lane & 15, quad = lane >> 4, ci0 = quad * 8;
    const int starts[4] = {0, 3, 6, 8};
    const int cnts[4]   = {3, 3, 2, 2};
    int widx = (wv + h0) & 3;
    int wst = starts[widx], wcnt = cnts[widx];

    int R0[3][2], s0[3][2];
#pragma unroll
    for (int w = 0; w < 3; ++w)
#pragma unroll
        for (int mt = 0; mt < 2; ++mt) {
            int row = mt * 16 + l15;
            int pos = row < 27 ? row : 26;
            int a = pos / 9, b = (pos / 3) % 3, c = pos % 3;
            int w0v = (w < wcnt) ? (wst + w) : wst;
            R0[w][mt] = ((2 + a) * 5 + (2 + b)) * 32 + (3 * w0v + 2 + c);
            s0[w][mt] = a + b + c + 6 + 3 * w0v;   // >= max dts (6)
        }

    float omax[3][4];
#pragma unroll
    for (int w = 0; w < 3; ++w)
#pragma unroll
        for (int nt = 0; nt < 4; ++nt) omax[w][nt] = -INFINITY;

    // tap-balanced halves: {1,2,4,7}=62 taps, {0,3,5,6}=63 taps
    const int clsl[2][4] = {{1, 2, 4, 7}, {0, 3, 5, 6}};
#pragma unroll 1
    for (int ic = 0; ic < 4; ++ic) {
        int cls = clsl[half][ic];
        int pd = (cls >> 2) & 1, ph = (cls >> 1) & 1, pw = cls & 1;
        int ntd = 3 - pd, nth = 3 - ph, ntw = 3 - pw;
        const unsigned short* wp = wtp + (size_t)cls * 27 * 2048;
        if (wcnt == 3) do_compute<3>(wp, Xs, R0, s0, quad, ci0, l15, ntd, nth, ntw, omax);
        else           do_compute<2>(wp, Xs, R0, s0, quad, ci0, l15, ntd, nth, ntw, omax);
    }

    if (quad == 0) {
        int elemBase = ((n * 5 + d0) * 10 + h0) * 10;
        for (int w = 0; w < wcnt; ++w) {
            int elem = elemBase + wst + w;
            float* pp = partial + ((size_t)(half * 8000 + elem)) * 64;
#pragma unroll
            for (int nt = 0; nt < 4; ++nt) pp[nt * 16 + l15] = omax[w][nt];
        }
    }
}

__global__ void finalize_k(const float* __restrict__ partial, const float* __restrict__ bias,
                           float* __restrict__ out)
{
    int tid = threadIdx.x;
    int el  = blockIdx.x * 4 + (tid >> 6);   // 2000 blocks, wave per elem
    int co  = tid & 63;
    float m = fmaxf(partial[(size_t)el * 64 + co],
                    partial[(size_t)(8000 + el) * 64 + co]);
    float v = m + bias[co];
#pragma unroll
    for (int off = 32; off > 0; off >>= 1) v += __shfl_xor(v, off);
    if (co == 0) out[el] = v;
}

// ---------------- fallback (round-1 kernel, no ws needed) ----------------
__global__ __launch_bounds__(256) void fused_fallback(
    const float* __restrict__ x, const float* __restrict__ wsrc,
    const float* __restrict__ bias, float* __restrict__ out)
{
    __shared__ float xs[CIN * 125];
    __shared__ float wmax[4][64];
    const int b  = blockIdx.x;
    const int w0 = b % 10, h0 = (b / 10) % 10, d0 = (b / 100) % 5, n = b / 500;
    const int tid = threadIdx.x;
    const int id0 = 3 * d0 - 1, ih0 = 3 * h0 - 1, iw0 = 3 * w0 - 1;
    for (int e = tid; e < CIN * 125; e += 256) {
        int kk = e % 5, jj = (e / 5) % 5, ii = (e / 25) % 5, c = e / 125;
        int id = id0 + ii, ih = ih0 + jj, iw = iw0 + kk;
        float v = 0.f;
        if (id >= 0 && ih >= 0 && iw >= 0)
            v = x[(((n * CIN + c) * D + id) * H + ih) * W + iw];
        xs[e] = v;
    }
    __syncthreads();
    const int lane = tid & 63, wv = tid >> 6;
    float lmax = -INFINITY;
    for (int ccls = 0; ccls < 2; ++ccls) {
        const int cls = wv * 2 + ccls;
        const int pd = (cls >> 2) & 1, ph = (cls >> 1) & 1, pw = cls & 1;
        float acc[27];
#pragma unroll
        for (int i = 0; i < 27; ++i) acc[i] = 0.f;
        for (int ci = 0; ci < CIN; ++ci) {
            float wr[27];
#pragma unroll
            for (int t = 0; t < 27; ++t) {
                int td = t / 9, th = (t / 3) % 3, tw = t % 3;
                int kd = pd + 2 * td, kh = ph + 2 * th, kw = pw + 2 * tw;
                wr[t] = (kd < 5 && kh < 5 && kw < 5)
                          ? wsrc[((ci * 64 + lane) * 125) + kd * 25 + kh * 5 + kw] : 0.f;
            }
            const float* xb = xs + ci * 125;
#pragma unroll
            for (int td = 0; td < 3; ++td)
#pragma unroll
            for (int th = 0; th < 3; ++th)
#pragma unroll
            for (int tw = 0; tw < 3; ++tw) {
                const float wval = wr[(td * 3 + th) * 3 + tw];
#pragma unroll
                for (int a = 0; a < 3; ++a)
#pragma unroll
                for (int bb = 0; bb < 3; ++bb)
#pragma unroll
                for (int cc = 0; cc < 3; ++cc)
                    acc[(a * 3 + bb) * 3 + cc] +=
                        xb[(a + 2 - td) * 25 + (bb + 2 - th) * 5 + (cc + 2 - tw)] * wval;
            }
        }
#pragma unroll
        for (int i = 0; i < 27; ++i) lmax = fmaxf(lmax, acc[i]);
    }
    wmax[wv][lane] = lmax;
    __syncthreads();
    if (wv == 0) {
        float m = fmaxf(fmaxf(wmax[0][lane], wmax[1][lane]),
                        fmaxf(wmax[2][lane], wmax[3][lane]));
        m += bias[lane];
        for (int off = 32; off > 0; off >>= 1) m += __shfl_down(m, off);
        if (lane == 0) out[b] = m;
    }
}

extern "C" void kernel_launch(void* const* d_in, const int* in_sizes, int n_in,
                              void* d_out, int out_size, void* d_ws, size_t ws_size,
                              hipStream_t stream) {
    const float* x    = (const float*)d_in[0];
    const float* w    = (const float*)d_in[1];
    const float* bias = (const float*)d_in[2];
    float* out = (float*)d_out;

    if (ws_size >= WS_NEED) {
        unsigned short* wtp = (unsigned short*)d_ws;
        unsigned short* xT  = (unsigned short*)((char*)d_ws + WS_XT_OFF);
        float* partial      = (float*)((char*)d_ws + WS_PART_OFF);
        prep_w<<<1728, 256, 0, stream>>>(w, wtp);
        transpose_x<<<8192, 256, 0, stream>>>(x, xT);
        main_k<<<1600, 256, 0, stream>>>(wtp, xT, partial);
        finalize_k<<<2000, 256, 0, stream>>>(partial, bias, out);
    } else {
        fused_fallback<<<8000, 256, 0, stream>>>(x, w, bias, out);
    }
}

// Round 7
// 206.154 us; speedup vs baseline: 3.1599x; 1.0485x over previous
//
#include <hip/hip_runtime.h>
#include <hip/hip_bf16.h>
#include <math.h>

typedef short bf16x8 __attribute__((ext_vector_type(8)));
typedef float f32x4 __attribute__((ext_vector_type(4)));

constexpr int CIN = 32, COUT = 64, D = 16, H = 32, W = 32;

// ---------------- ws layout ----------------
// [0, 884736)          : wtp bf16 [cls8][t27][co64][ci32]
// [1MB, 1MB+33554432)  : xT  bf16 [n16][id16][ih32][iw32][ci32]
constexpr size_t WS_XT_OFF = 1u << 20;
constexpr size_t WS_NEED   = WS_XT_OFF + 33554432u;

// Per-wave item lists: item = (cls, alpha), code = cls + alpha*8.
// chunks per item = Pi(cls); per-wave totals: 93, 86, 98, 98 (of 375).
static __device__ const unsigned char IT_CODE[24] = {
    0, 8, 16, 3,                  // w0: cls0 a0,a1,a2 ; cls3 a0          = 93
    1, 9, 17, 11, 19, 7,          // w1: cls1 x3 ; cls3 a1,a2 ; cls7 a0  = 86
    2, 10, 18, 5, 13, 21, 15,     // w2: cls2 x3 ; cls5 x3 ; cls7 a1     = 98
    4, 12, 20, 6, 14, 22, 23};    // w3: cls4 x3 ; cls6 x3 ; cls7 a2     = 98
static __device__ const unsigned char IT_START[5] = {0, 4, 10, 17, 24};
// epilogue: window -> contiguous entry range in the (g,slot) sequence e=0..14
static __device__ const unsigned char EPI_START[10] = {0, 1, 3, 5, 6, 7, 9, 11, 12, 13};
static __device__ const unsigned char EPI_CNT[10]   = {1, 2, 2, 1, 1, 2, 2, 1, 1, 2};

// Combined prep: blocks [0,8192) transpose x -> xT; blocks [8192,9920) pack weights.
__global__ void prep_all(const float* __restrict__ x, const float* __restrict__ w,
                         unsigned short* __restrict__ xT, unsigned short* __restrict__ wtp) {
    __shared__ float tile[32 * 33];
    int tid = threadIdx.x;
    if (blockIdx.x < 8192) {
        int bid = blockIdx.x;                    // n*512 + id*32 + ih
        int ih = bid & 31, id = (bid >> 5) & 15, n = bid >> 9;
        int lw = tid & 31, g = tid >> 5;         // g in [0,8)
#pragma unroll
        for (int p = 0; p < 4; ++p) {
            int ci = g + p * 8;
            tile[lw * 33 + ci] = x[((((size_t)n * CIN + ci) * D + id) * H + ih) * W + lw];
        }
        __syncthreads();
        unsigned short* op = xT + ((((size_t)n * D + id) * H + ih) * W) * CIN;
#pragma unroll
        for (int p = 0; p < 4; ++p) {
            int iw = g + p * 8;
            __hip_bfloat16 b = __float2bfloat16(tile[iw * 33 + lw]);
            op[iw * 32 + lw] = *reinterpret_cast<unsigned short*>(&b);
        }
    } else {
        int idx = (blockIdx.x - 8192) * 256 + tid;   // 442368 total
        int ci  = idx & 31;
        int co  = (idx >> 5) & 63;
        int tt  = idx >> 11;                          // cls*27 + t
        int t   = tt % 27, cls = tt / 27;
        int td = t / 9, th = (t / 3) % 3, tw = t % 3;
        int pd = (cls >> 2) & 1, ph = (cls >> 1) & 1, pw = cls & 1;
        int kd = pd + 2 * td, kh = ph + 2 * th, kw = pw + 2 * tw;
        float v = 0.f;
        if (kd < 5 && kh < 5 && kw < 5)
            v = w[(ci * COUT + co) * 125 + kd * 25 + kh * 5 + kw];
        __hip_bfloat16 b = __float2bfloat16(v);
        wtp[idx] = *reinterpret_cast<unsigned short*>(&b);
    }
}

__global__ __launch_bounds__(256, 2) void main_k(
    const unsigned short* __restrict__ wtp, const unsigned short* __restrict__ xT,
    const float* __restrict__ bias, float* __restrict__ out)
{
    __shared__ unsigned short Xs[25600];   // 51200 B; epilogue reuses first 16 KB
    int bx = blockIdx.x;                   // (n*5+d0)*10 + h0, 800 total
    int h0 = bx % 10;
    int d0 = (bx / 10) % 5;
    int n  = bx / 50;
    int tid = threadIdx.x;

    // ---- stage Xs [dd5][hl5][ww32][ci32], linear (no swizzle) ----
    int id0 = 3 * d0 - 1, ih0 = 3 * h0 - 1;
    for (int i = tid; i < 3200; i += 256) {
        int cb = i & 3, ww = (i >> 2) & 31, hl = (i >> 7) % 5, dd = i / 640;
        int id = id0 + dd, ih = ih0 + hl, iw = ww - 1;
        float4 v = {0.f, 0.f, 0.f, 0.f};
        if (id >= 0 && ih >= 0 && iw >= 0)
            v = ((const float4*)(xT + ((((size_t)n * D + id) * H + ih) * W + iw) * 32))[cb];
        ((float4*)Xs)[i] = v;
    }

    int lane = tid & 63, wv = tid >> 6;
    int l15 = lane & 15, quad = lane >> 4;
    int wv_s = __builtin_amdgcn_readfirstlane(wv);

    // A lane offsets (bytes): row m = mt*16+l15 (clamped to 29), ci-chunk = quad
    int loff0 = l15 * 64 + quad * 16;
    int m1 = 16 + l15; if (m1 > 29) m1 = 29;
    int loff1 = m1 * 64 + quad * 16;
    // B lane offset (bytes) into a tap tile [co64][ci32]: co=nt*16+l15, ci=quad*8
    int laneB = l15 * 64 + quad * 16;

    f32x4 mx[2][4];
#pragma unroll
    for (int mt = 0; mt < 2; ++mt)
#pragma unroll
        for (int nt = 0; nt < 4; ++nt) mx[mt][nt] = (f32x4){-INFINITY, -INFINITY, -INFINITY, -INFINITY};

    __syncthreads();
    const char* xsb = (const char*)Xs;

    int it0 = IT_START[wv_s], it1 = IT_START[wv_s + 1];
#pragma unroll 1
    for (int ii = it0; ii < it1; ++ii) {
        int code  = __builtin_amdgcn_readfirstlane(IT_CODE[ii]);
        int cls   = code & 7;
        int alpha = code >> 3;
        int ntd = 3 - ((cls >> 2) & 1), nth = 3 - ((cls >> 1) & 1), ntw = 3 - (cls & 1);
        const char* tbb = (const char*)wtp + (size_t)cls * 27 * 4096 + laneB;

        f32x4 acc[3][2][4];
#pragma unroll
        for (int b = 0; b < 3; ++b)
#pragma unroll
            for (int mt = 0; mt < 2; ++mt)
#pragma unroll
                for (int nt = 0; nt < 4; ++nt) acc[b][mt][nt] = (f32x4){0.f, 0.f, 0.f, 0.f};

        const int T = ntd * nth * ntw;
        // prefetch chunk 0: tap (0,0,0)
        bf16x8 nb0 = *(const bf16x8*)(tbb);
        bf16x8 nb1 = *(const bf16x8*)(tbb + 1024);
        bf16x8 nb2 = *(const bf16x8*)(tbb + 2048);
        bf16x8 nb3 = *(const bf16x8*)(tbb + 3072);
        int ptd = 0, pth = 0, ptw = 0;
        int nS = ((alpha + 2) * 5 + 2) * 2048 + 2 * 64;

#pragma unroll 1
        for (int it = 0; it < T; ++it) {
            bf16x8 b0 = nb0, b1 = nb1, b2 = nb2, b3 = nb3;
            const int S = nS;

            if (it + 1 < T) {
                ++ptw;
                if (ptw == ntw) { ptw = 0; ++pth; if (pth == nth) { pth = 0; ++ptd; } }
            }
            nS = ((alpha + 2 - ptd) * 5 + (2 - pth)) * 2048 + (2 - ptw) * 64;
            const char* bq = tbb + (ptd * 9 + pth * 3 + ptw) * 4096;
            nb0 = *(const bf16x8*)(bq);
            nb1 = *(const bf16x8*)(bq + 1024);
            nb2 = *(const bf16x8*)(bq + 2048);
            nb3 = *(const bf16x8*)(bq + 3072);

#pragma unroll
            for (int beta = 0; beta < 3; ++beta) {
                const char* rb = xsb + S + beta * 2048;
                bf16x8 af0 = *(const bf16x8*)(rb + loff0);
                bf16x8 af1 = *(const bf16x8*)(rb + loff1);
                acc[beta][0][0] = __builtin_amdgcn_mfma_f32_16x16x32_bf16(af0, b0, acc[beta][0][0], 0, 0, 0);
                acc[beta][0][1] = __builtin_amdgcn_mfma_f32_16x16x32_bf16(af0, b1, acc[beta][0][1], 0, 0, 0);
                acc[beta][0][2] = __builtin_amdgcn_mfma_f32_16x16x32_bf16(af0, b2, acc[beta][0][2], 0, 0, 0);
                acc[beta][0][3] = __builtin_amdgcn_mfma_f32_16x16x32_bf16(af0, b3, acc[beta][0][3], 0, 0, 0);
                acc[beta][1][0] = __builtin_amdgcn_mfma_f32_16x16x32_bf16(af1, b0, acc[beta][1][0], 0, 0, 0);
                acc[beta][1][1] = __builtin_amdgcn_mfma_f32_16x16x32_bf16(af1, b1, acc[beta][1][1], 0, 0, 0);
                acc[beta][1][2] = __builtin_amdgcn_mfma_f32_16x16x32_bf16(af1, b2, acc[beta][1][2], 0, 0, 0);
                acc[beta][1][3] = __builtin_amdgcn_mfma_f32_16x16x32_bf16(af1, b3, acc[beta][1][3], 0, 0, 0);
            }
        }

        // fold item into running max (same (m,co) mapping for every item)
#pragma unroll
        for (int mt = 0; mt < 2; ++mt)
#pragma unroll
            for (int nt = 0; nt < 4; ++nt)
#pragma unroll
                for (int r = 0; r < 4; ++r) {
                    float m = fmaxf(fmaxf(acc[0][mt][nt][r], acc[1][mt][nt][r]), acc[2][mt][nt][r]);
                    mx[mt][nt][r] = fmaxf(mx[mt][nt][r], m);
                }
    }

    // ---- epilogue: gamma->window fold, cross-wave max, bias, co-sum ----
    __syncthreads();                 // Xs reads done; reuse as epi buffer
    float* epi = (float*)Xs;
    int fsm0 = (0x3123 >> (quad * 4)) & 15;   // rows-in-first-window, mt0: 3,2,1,3
    int fsm1 = (0x4312 >> (quad * 4)) & 15;   // mt1: 2,1,3,4
#pragma unroll
    for (int mt = 0; mt < 2; ++mt) {
        int fs = mt ? fsm1 : fsm0;
        int g  = mt * 4 + quad;
#pragma unroll
        for (int nt = 0; nt < 4; ++nt) {
            float a0 = mx[mt][nt][0], a1 = mx[mt][nt][1], a2 = mx[mt][nt][2], a3 = mx[mt][nt][3];
            float t01 = fmaxf(a0, a1), t012 = fmaxf(t01, a2), t0123 = fmaxf(t012, a3);
            float pA = fs == 1 ? a0 : (fs == 2 ? t01 : (fs == 3 ? t012 : t0123));
            float t23 = fmaxf(a2, a3), t123 = fmaxf(a1, t23);
            float pB = fs == 1 ? t123 : (fs == 2 ? t23 : (fs == 3 ? a3 : -INFINITY));
            epi[((wv * 8 + g) * 2 + 0) * 64 + nt * 16 + l15] = pA;
            epi[((wv * 8 + g) * 2 + 1) * 64 + nt * 16 + l15] = pB;
        }
    }
    __syncthreads();

    int elemBase = ((n * 5 + d0) * 10 + h0) * 10;
    float bco = bias[lane];
#pragma unroll 1
    for (int win = wv_s; win < 10; win += 4) {
        int st = EPI_START[win], cnt = EPI_CNT[win];
        float v = -INFINITY;
        for (int src = 0; src < 4; ++src)
            for (int e = st; e < st + cnt; ++e)
                v = fmaxf(v, epi[(src * 16 + e) * 64 + lane]);
        v += bco;
#pragma unroll
        for (int off = 32; off > 0; off >>= 1) v += __shfl_xor(v, off);
        if (lane == 0) out[elemBase + win] = v;
    }
}

// ---------------- fallback (round-1 kernel, no ws needed) ----------------
__global__ __launch_bounds__(256) void fused_fallback(
    const float* __restrict__ x, const float* __restrict__ wsrc,
    const float* __restrict__ bias, float* __restrict__ out)
{
    __shared__ float xs[CIN * 125];
    __shared__ float wmax[4][64];
    const int b  = blockIdx.x;
    const int w0 = b % 10, h0 = (b / 10) % 10, d0 = (b / 100) % 5, n = b / 500;
    const int tid = threadIdx.x;
    const int id0 = 3 * d0 - 1, ih0 = 3 * h0 - 1, iw0 = 3 * w0 - 1;
    for (int e = tid; e < CIN * 125; e += 256) {
        int kk = e % 5, jj = (e / 5) % 5, ii = (e / 25) % 5, c = e / 125;
        int id = id0 + ii, ih = ih0 + jj, iw = iw0 + kk;
        float v = 0.f;
        if (id >= 0 && ih >= 0 && iw >= 0)
            v = x[(((n * CIN + c) * D + id) * H + ih) * W + iw];
        xs[e] = v;
    }
    __syncthreads();
    const int lane = tid & 63, wv = tid >> 6;
    float lmax = -INFINITY;
    for (int ccls = 0; ccls < 2; ++ccls) {
        const int cls = wv * 2 + ccls;
        const int pd = (cls >> 2) & 1, ph = (cls >> 1) & 1, pw = cls & 1;
        float acc[27];
#pragma unroll
        for (int i = 0; i < 27; ++i) acc[i] = 0.f;
        for (int ci = 0; ci < CIN; ++ci) {
            float wr[27];
#pragma unroll
            for (int t = 0; t < 27; ++t) {
                int td = t / 9, th = (t / 3) % 3, tw = t % 3;
                int kd = pd + 2 * td, kh = ph + 2 * th, kw = pw + 2 * tw;
                wr[t] = (kd < 5 && kh < 5 && kw < 5)
                          ? wsrc[((ci * 64 + lane) * 125) + kd * 25 + kh * 5 + kw] : 0.f;
            }
            const float* xb = xs + ci * 125;
#pragma unroll
            for (int td = 0; td < 3; ++td)
#pragma unroll
            for (int th = 0; th < 3; ++th)
#pragma unroll
            for (int tw = 0; tw < 3; ++tw) {
                const float wval = wr[(td * 3 + th) * 3 + tw];
#pragma unroll
                for (int a = 0; a < 3; ++a)
#pragma unroll
                for (int bb = 0; bb < 3; ++bb)
#pragma unroll
                for (int cc = 0; cc < 3; ++cc)
                    acc[(a * 3 + bb) * 3 + cc] +=
                        xb[(a + 2 - td) * 25 + (bb + 2 - th) * 5 + (cc + 2 - tw)] * wval;
            }
        }
#pragma unroll
        for (int i = 0; i < 27; ++i) lmax = fmaxf(lmax, acc[i]);
    }
    wmax[wv][lane] = lmax;
    __syncthreads();
    if (wv == 0) {
        float m = fmaxf(fmaxf(wmax[0][lane], wmax[1][lane]),
                        fmaxf(wmax[2][lane], wmax[3][lane]));
        m += bias[lane];
        for (int off = 32; off > 0; off >>= 1) m += __shfl_down(m, off);
        if (lane == 0) out[b] = m;
    }
}

extern "C" void kernel_launch(void* const* d_in, const int* in_sizes, int n_in,
                              void* d_out, int out_size, void* d_ws, size_t ws_size,
                              hipStream_t stream) {
    const float* x    = (const float*)d_in[0];
    const float* w    = (const float*)d_in[1];
    const float* bias = (const float*)d_in[2];
    float* out = (float*)d_out;

    if (ws_size >= WS_NEED) {
        unsigned short* wtp = (unsigned short*)d_ws;
        unsigned short* xT  = (unsigned short*)((char*)d_ws + WS_XT_OFF);
        prep_all<<<9920, 256, 0, stream>>>(x, w, xT, wtp);
        main_k<<<800, 256, 0, stream>>>(wtp, xT, bias, out);
    } else {
        fused_fallback<<<8000, 256, 0, stream>>>(x, w, bias, out);
    }
}